// Round 1
// baseline (847.494 us; speedup 1.0000x reference)
//
#include <hip/hip_runtime.h>
#include <hip/hip_bf16.h>

#define N_NODES 100000
#define N_EDGES 3200000
#define N_GRAPHS 512
#define HID 64
#define OUT_DIM 10

// ---------------------------------------------------------------------------
// K1: in-degree histogram over dst
__global__ void k_deg(const int* __restrict__ dst, unsigned* __restrict__ cnt) {
    int e = blockIdx.x * blockDim.x + threadIdx.x;
    if (e < N_EDGES) atomicAdd(&cnt[dst[e]], 1u);
}

// K2: dinv = 1/sqrt(deg+1) (self loop), g1 = dinv*x
__global__ void k_dinv(const unsigned* __restrict__ cnt, const float* __restrict__ x,
                       float* __restrict__ dinv, float* __restrict__ g1) {
    int i = blockIdx.x * blockDim.x + threadIdx.x;
    if (i < N_NODES) {
        float d = 1.0f / sqrtf((float)cnt[i] + 1.0f);
        dinv[i] = d;
        g1[i] = d * x[i];
    }
}

// K3: single-block exclusive scan of cnt -> off (CSR row offsets)
__global__ __launch_bounds__(1024) void k_scan(const unsigned* __restrict__ cnt,
                                               int* __restrict__ off) {
    __shared__ int part[1024];
    const int T = 1024;
    int t = threadIdx.x;
    const int chunk = (N_NODES + T - 1) / T;
    int lo = t * chunk;
    int hi = lo + chunk; if (hi > N_NODES) hi = N_NODES;
    int sacc = 0;
    for (int i = lo; i < hi; i++) sacc += (int)cnt[i];
    part[t] = sacc;
    __syncthreads();
    for (int d = 1; d < T; d <<= 1) {
        int v = (t >= d) ? part[t - d] : 0;
        __syncthreads();
        part[t] += v;
        __syncthreads();
    }
    int run = (t == 0) ? 0 : part[t - 1];
    for (int i = lo; i < hi; i++) { off[i] = run; run += (int)cnt[i]; }
    if (t == T - 1) off[N_NODES] = part[T - 1];
}

// K4: scatter edges into CSR by dst
__global__ void k_scatter(const int* __restrict__ src, const int* __restrict__ dst,
                          const int* __restrict__ off, unsigned* __restrict__ cursor,
                          int* __restrict__ csr) {
    int e = blockIdx.x * blockDim.x + threadIdx.x;
    if (e < N_EDGES) {
        int d = dst[e];
        unsigned p = atomicAdd(&cursor[d], 1u);
        csr[off[d] + p] = src[e];
    }
}

// K5: layer-1 scalar aggregation. One wave per node, lanes parallel over edges.
// s[d] = dinv[d] * ( sum_e dinv[src]*x[src] + dinv[d]*x[d] ); store (s, dinv).
__global__ __launch_bounds__(256) void k_layer1(const int* __restrict__ csr,
                                                const int* __restrict__ off,
                                                const float* __restrict__ g1,
                                                const float* __restrict__ dinv,
                                                const float* __restrict__ x,
                                                float2* __restrict__ sd) {
    int wid = (blockIdx.x * blockDim.x + threadIdx.x) >> 6;
    int lane = threadIdx.x & 63;
    if (wid >= N_NODES) return;
    wid = __builtin_amdgcn_readfirstlane(wid);
    int lo = off[wid], hi = off[wid + 1];
    float acc = 0.f;
    for (int p = lo + lane; p < hi; p += 64) acc += g1[csr[p]];
    #pragma unroll
    for (int o = 32; o > 0; o >>= 1) acc += __shfl_down(acc, o, 64);
    if (lane == 0) {
        float dn = dinv[wid];
        float s = dn * (acc + dn * x[wid]);
        sd[wid] = make_float2(s, dn);
    }
}

// K6: layer-2 aggregation. One wave per node; lane j owns channel j.
// agg[d][j] = dinv[d]*( sum_e dinv[src]*relu(s[src]*W1[j]+b1[j]) + dinv[d]*relu(s[d]*W1[j]+b1[j]) )
__global__ __launch_bounds__(256) void k_layer2(const int* __restrict__ csr,
                                                const int* __restrict__ off,
                                                const float2* __restrict__ sd,
                                                const float* __restrict__ W1,
                                                const float* __restrict__ b1,
                                                float* __restrict__ agg) {
    int wid = (blockIdx.x * blockDim.x + threadIdx.x) >> 6;
    int lane = threadIdx.x & 63;
    if (wid >= N_NODES) return;
    wid = __builtin_amdgcn_readfirstlane(wid);
    float w = W1[lane], b = b1[lane];
    int lo = off[wid], hi = off[wid + 1];
    float acc = 0.f;
    for (int p = lo; p < hi; p++) {
        int sI = csr[p];                    // uniform across wave -> scalar load
        float2 v = sd[sI];
        float t = fmaxf(fmaf(v.x, w, b), 0.f);
        acc = fmaf(v.y, t, acc);
    }
    float2 self = sd[wid];
    float t = fmaxf(fmaf(self.x, w, b), 0.f);
    acc = fmaf(self.y, t, acc);
    agg[wid * HID + lane] = self.y * acc;
}

// K7: x2 = relu(agg @ W2 + b2), in place on agg. One wave per node, lane j owns out ch.
__global__ __launch_bounds__(256) void k_x2(float* __restrict__ agg,
                                            const float* __restrict__ W2,
                                            const float* __restrict__ b2) {
    __shared__ float w2s[HID * HID];
    for (int i = threadIdx.x; i < HID * HID; i += blockDim.x) w2s[i] = W2[i];
    __syncthreads();
    int wid = (blockIdx.x * blockDim.x + threadIdx.x) >> 6;
    int lane = threadIdx.x & 63;
    if (wid >= N_NODES) return;
    wid = __builtin_amdgcn_readfirstlane(wid);
    const float* row = agg + (size_t)wid * HID;
    float acc = b2[lane];
    #pragma unroll 8
    for (int k = 0; k < HID; k++) acc = fmaf(row[k], w2s[k * HID + lane], acc);
    float x2v = fmaxf(acc, 0.f);
    agg[(size_t)wid * HID + lane] = x2v;   // all reads of row done before this (lockstep wave)
}

// K8: graph segment boundaries from sorted batch. gstart[g] = first i with batch[i] >= g.
__global__ void k_bounds(const int* __restrict__ batch, int* __restrict__ gstart) {
    int i = blockIdx.x * blockDim.x + threadIdx.x;
    if (i >= N_NODES) return;
    int b = batch[i];
    if (i == 0) {
        for (int g = 0; g <= b; g++) gstart[g] = 0;
    } else {
        int pb = batch[i - 1];
        for (int g = pb + 1; g <= b; g++) gstart[g] = i;
    }
    if (i == N_NODES - 1) {
        for (int g = b + 1; g <= N_GRAPHS; g++) gstart[g] = N_NODES;
    }
}

// K9: fused mean-pool + linear head. One block (128 thr) per graph.
// thread t<64 accumulates x1[n][t] (recomputed from s); t>=64 accumulates x2[n][t-64].
__global__ __launch_bounds__(128) void k_pool(const float* __restrict__ x2,
                                              const float2* __restrict__ sd,
                                              const float* __restrict__ W1,
                                              const float* __restrict__ b1,
                                              const int* __restrict__ gstart,
                                              const float* __restrict__ Wl,
                                              const float* __restrict__ bl,
                                              float* __restrict__ out) {
    int g = blockIdx.x;
    int t = threadIdx.x;
    int lo = gstart[g], hi = gstart[g + 1];
    float w = 0.f, b = 0.f;
    if (t < HID) { w = W1[t]; b = b1[t]; }
    float acc = 0.f;
    if (t < HID) {
        for (int n = lo; n < hi; n++) {
            float s = sd[n].x;
            acc += fmaxf(fmaf(s, w, b), 0.f);
        }
    } else {
        int j = t - HID;
        for (int n = lo; n < hi; n++) acc += x2[(size_t)n * HID + j];
    }
    float cntg = (float)(hi - lo);
    float pooled = acc / fmaxf(cntg, 1.0f);
    __shared__ float pl[2 * HID];
    pl[t] = pooled;
    __syncthreads();
    if (t < OUT_DIM) {
        float r = bl[t];
        #pragma unroll 16
        for (int j = 0; j < 2 * HID; j++) r = fmaf(pl[j], Wl[j * OUT_DIM + t], r);
        out[g * OUT_DIM + t] = r;
    }
}

// ---------------------------------------------------------------------------
extern "C" void kernel_launch(void* const* d_in, const int* in_sizes, int n_in,
                              void* d_out, int out_size, void* d_ws, size_t ws_size,
                              hipStream_t stream) {
    const float* x      = (const float*)d_in[0];
    const int*   ei     = (const int*)d_in[1];           // (2, E) int32
    const int*   batch  = (const int*)d_in[2];
    const float* W1     = (const float*)d_in[3];
    const float* b1     = (const float*)d_in[4];
    const float* W2     = (const float*)d_in[5];
    const float* b2     = (const float*)d_in[6];
    const float* Wl     = (const float*)d_in[7];
    const float* bl     = (const float*)d_in[8];
    float* out = (float*)d_out;

    const int* src = ei;
    const int* dst = ei + N_EDGES;

    // workspace carve-up (256B aligned)
    char* p = (char*)d_ws;
    auto alloc = [&](size_t bytes) { void* r = (void*)p; p += (bytes + 255) & ~(size_t)255; return r; };
    unsigned* cnt    = (unsigned*)alloc(N_NODES * 4);
    unsigned* cursor = (unsigned*)alloc(N_NODES * 4);
    int*      off    = (int*)alloc((N_NODES + 1) * 4);
    int*      csr    = (int*)alloc((size_t)N_EDGES * 4);
    float*    dinv   = (float*)alloc(N_NODES * 4);
    float*    g1     = (float*)alloc(N_NODES * 4);
    float2*   sd     = (float2*)alloc((size_t)N_NODES * 8);
    float*    agg    = (float*)alloc((size_t)N_NODES * HID * 4);
    int*      gstart = (int*)alloc((N_GRAPHS + 1) * 4);

    hipMemsetAsync(cnt, 0, N_NODES * 4, stream);
    hipMemsetAsync(cursor, 0, N_NODES * 4, stream);

    const int TB = 256;
    int ebl = (N_EDGES + TB - 1) / TB;
    int nbl = (N_NODES + TB - 1) / TB;
    int wbl = (N_NODES * 64 + TB - 1) / TB;   // wave-per-node kernels

    k_deg<<<ebl, TB, 0, stream>>>(dst, cnt);
    k_dinv<<<nbl, TB, 0, stream>>>(cnt, x, dinv, g1);
    k_scan<<<1, 1024, 0, stream>>>(cnt, off);
    k_scatter<<<ebl, TB, 0, stream>>>(src, dst, off, cursor, csr);
    k_layer1<<<wbl, TB, 0, stream>>>(csr, off, g1, dinv, x, sd);
    k_layer2<<<wbl, TB, 0, stream>>>(csr, off, sd, W1, b1, agg);
    k_x2<<<wbl, TB, 0, stream>>>(agg, W2, b2);
    k_bounds<<<nbl, TB, 0, stream>>>(batch, gstart);
    k_pool<<<N_GRAPHS, 128, 0, stream>>>(agg, sd, W1, b1, gstart, Wl, bl, out);
}